// Round 11
// baseline (272.520 us; speedup 1.0000x reference)
//
#include <hip/hip_runtime.h>

// Grouped GRU: G=64, D=16, H=8, B=64, T=512.
// R18 = R17 + dual-stream consumer + gx prefetch.
//
// R17 evidence (first run of producer/consumer): 119.9us, VALUBusy 40%,
// LDS 12288, 0 bank conflicts. Wall=562 cyc/step; consumer issue ~145,
// producer ~100 (model matches composite VALUBusy). Consumer stalls ~400
// cyc/step: ~120 ds_read-at-use latency + ~110 serial chain (gh depth + 4
// serial trans) + in-order-issue serialization (a lone wave has NOTHING
// independent behind a stalled chain instruction - waves issue in order;
// only compile-time interleaved independent work fills chain stalls).
// Change: (a) consumer wave now runs TWO independent recurrence streams
// (A=cells 0-7, B=cells 8-15) hand-interleaved per step - B's issue fills
// A's stalls; 256 consumer waves handle all 4096 cells. Block = 192 thr =
// 1 consumer + 2 producers (each producer = R17 verbatim, 8 cells).
// (b) gx prefetched one step ahead into registers (6 ds_reads issued a full
// step before use; only j=0-per-chunk stays exposed, 1/8 amortized).
// Body model: max(2x145 issue, chain 110) ~300-350 cyc/step.
// Predicted: dur 119.9 -> 62-85us, VALUBusy 50-65%, LDS 24576, VGPR ~130,
// FETCH/WRITE/absmax unchanged. Null (~120us, VALUBusy 40%) => scheduler
// failed to interleave A/B -> force with finer braiding next.
//
// Carried: raw s_barrier + lgkmcnt(0) sync (no vmcnt drain - keeps producer
// prefetch alive); producer 2-chunk named xrA/xrB ring (rule #20); R7 gate
// semantics (b_hh_n inside r*(...)); scales pre-folded (-log2e r,z; +2log2e n).

#define Gn 64
#define Dn 16
#define Hn 8
#define Tn 512
#define CHUNK 8
#define NCH (Tn / CHUNK)   // 64 chunks

typedef float v2f __attribute__((ext_vector_type(2)));

__device__ __forceinline__ float rcp_fast(float v) { return __builtin_amdgcn_rcpf(v); }
__device__ __forceinline__ float exp2_fast(float v) { return __builtin_amdgcn_exp2f(v); }

#define KNL (-1.44269504088896340736f)   // -log2(e)
#define KP2 ( 2.88539008177792681472f)   // +2*log2(e)

template <int CTRL>
__device__ __forceinline__ float dppf(float v) {
    return __int_as_float(
        __builtin_amdgcn_update_dpp(0, __float_as_int(v), CTRL, 0xF, 0xF, false));
}
template <int CTRL>
__device__ __forceinline__ v2f dpp2(v2f v) {
    v2f r;
    r.x = dppf<CTRL>(v.x);
    r.y = dppf<CTRL>(v.y);
    return r;
}

// Barrier WITHOUT vmcnt drain: LDS visibility needs lgkmcnt(0) only.
__device__ __forceinline__ void sync_lds() {
    asm volatile("s_waitcnt lgkmcnt(0)" ::: "memory");
    __builtin_amdgcn_s_barrier();
}

__global__ __attribute__((amdgpu_flat_work_group_size(192, 192),
                          amdgpu_waves_per_eu(1, 1)))
void mcgru_kernel(
    const float* __restrict__ x,     // [B, T, G*D]
    const float* __restrict__ W_ih,  // [G, 3H, D]
    const float* __restrict__ W_hh,  // [G, 3H, H]
    const float* __restrict__ b_ih,  // [G, 3H]
    const float* __restrict__ b_hh,  // [G, 3H]
    float* __restrict__ out)         // [B, T, G, H]
{
    // gx ring: [buffer][step][gate][128 lanes: producerA 0-63, producerB 64-127]
    __shared__ float gxs[2][CHUNK][3][128];

    const int tlane = threadIdx.x & 63;
    const int wid   = threadIdx.x >> 6;      // 0 = consumer, 1/2 = producers
    const int c     = tlane >> 3;            // cell slot within wave (0..7)
    const int u     = tlane & 7;             // hidden unit / octet lane
    const int s4 = u & 3, q = u >> 2;

    // DPP gather order within an aligned octet: slot k arrives from lane
    // u ^ mk, mk = {0,1,2,3,7,6,5,4}.
    int jmap[8];
#pragma unroll
    for (int k = 0; k < 8; ++k) {
        const int hi2 = k >> 2, r = k & 3;
        jmap[k] = ((q ^ hi2) << 2) | (s4 ^ r ^ (hi2 ? 3 : 0));
    }
    const float scale[3] = {KNL, KNL, KP2};

    if (wid >= 1) {
        // ------------- producer wave (R17 verbatim, cells offset) -------------
        const int cell = blockIdx.x * 16 + (wid - 1) * 8 + c;
        const int g    = cell & (Gn - 1);
        const int b    = cell >> 6;

        v2f wih[3][8];
        float bs[3];
#pragma unroll
        for (int qg = 0; qg < 3; ++qg) {
            const int row = qg * Hn + u;
            const float sc = scale[qg];
            const float* wr = W_ih + ((size_t)g * 24 + row) * Dn;
#pragma unroll
            for (int k = 0; k < 8; ++k) {
                const int dp = jmap[k] * 2;
                wih[qg][k] = (v2f){wr[dp] * sc, wr[dp + 1] * sc};
            }
            bs[qg] = (qg < 2)
                ? (b_ih[g * 24 + row] + b_hh[g * 24 + row]) * sc
                : b_ih[g * 24 + row] * sc;   // n: input-side bias only
        }
#pragma unroll
        for (int qg = 0; qg < 3; ++qg) {
#pragma unroll
            for (int i = 0; i < 8; ++i) asm volatile("" : "+v"(wih[qg][i]));
            asm volatile("" : "+v"(bs[qg]));
        }

        const int lds_off = (wid - 1) * 64 + tlane;
        const float* xq = x + ((size_t)b * Tn * Gn + g) * Dn + 2 * u;
        auto load_x = [&](int t) -> v2f {
            return *(const v2f*)(xq + (size_t)t * (Gn * Dn));
        };
        auto proj_store = [&](v2f xv, float* dst) {
            v2f X[8];
            X[0] = xv;
            X[1] = dpp2<0xB1>(xv);
            X[2] = dpp2<0x4E>(xv);
            X[3] = dpp2<0x1B>(xv);
            X[4] = dpp2<0x141>(X[0]);
            X[5] = dpp2<0x141>(X[1]);
            X[6] = dpp2<0x141>(X[2]);
            X[7] = dpp2<0x141>(X[3]);
#pragma unroll
            for (int qg = 0; qg < 3; ++qg) {
                v2f acc = wih[qg][0] * X[0];
#pragma unroll
                for (int i = 1; i < 8; ++i) acc += wih[qg][i] * X[i];  // pk_fma
                dst[qg * 128] = (bs[qg] + acc.x) + acc.y;              // ds_write
            }
        };

        v2f xrA[CHUNK], xrB[CHUNK];   // named 2-chunk ring (rule #20)
#pragma unroll
        for (int j = 0; j < CHUNK; ++j) xrA[j] = load_x(j);
#pragma unroll
        for (int j = 0; j < CHUNK; ++j) xrB[j] = load_x(CHUNK + j);
#pragma unroll
        for (int j = 0; j < CHUNK; ++j)
            proj_store(xrA[j], &gxs[0][j][0][lds_off]);
        sync_lds();   // chunk 0 ready

        for (int k = 0; k < NCH; k += 2) {
            if (k + 1 < NCH) {
#pragma unroll
                for (int j = 0; j < CHUNK; ++j)
                    proj_store(xrB[j], &gxs[1][j][0][lds_off]);
            }
            if (k + 2 < NCH) {
#pragma unroll
                for (int j = 0; j < CHUNK; ++j)
                    xrA[j] = load_x((k + 2) * CHUNK + j);
            }
            sync_lds();
            if (k + 2 < NCH) {
#pragma unroll
                for (int j = 0; j < CHUNK; ++j)
                    proj_store(xrA[j], &gxs[0][j][0][lds_off]);
            }
            if (k + 3 < NCH) {
#pragma unroll
                for (int j = 0; j < CHUNK; ++j)
                    xrB[j] = load_x((k + 3) * CHUNK + j);
            }
            sync_lds();
        }
    } else {
        // -------- consumer wave: TWO interleaved recurrence streams --------
        const int cellA = blockIdx.x * 16 + c;        // producer-1 cells
        const int cellB = cellA + 8;                  // producer-2 cells
        const int gA = cellA & (Gn - 1), bA = cellA >> 6;
        const int gB = cellB & (Gn - 1), bB = cellB >> 6;

        float whhA[3][8], whhB[3][8], bhnA, bhnB;
#pragma unroll
        for (int qg = 0; qg < 3; ++qg) {
            const int row = qg * Hn + u;
            const float sc = scale[qg];
            const float* hrA = W_hh + ((size_t)gA * 24 + row) * Hn;
            const float* hrB = W_hh + ((size_t)gB * 24 + row) * Hn;
#pragma unroll
            for (int k = 0; k < 8; ++k) {
                whhA[qg][k] = hrA[jmap[k]] * sc;
                whhB[qg][k] = hrB[jmap[k]] * sc;
            }
        }
        bhnA = b_hh[gA * 24 + 2 * Hn + u] * KP2;   // stays inside r*(...)
        bhnB = b_hh[gB * 24 + 2 * Hn + u] * KP2;
#pragma unroll
        for (int qg = 0; qg < 3; ++qg)
#pragma unroll
            for (int k = 0; k < 8; ++k) {
                asm volatile("" : "+v"(whhA[qg][k]));
                asm volatile("" : "+v"(whhB[qg][k]));
            }
        asm volatile("" : "+v"(bhnA));
        asm volatile("" : "+v"(bhnB));

        float* opA = out + ((size_t)bA * Tn * Gn + gA) * Hn + u;
        float* opB = out + ((size_t)bB * Tn * Gn + gB) * Hn + u;
        float hA = 0.0f, hB = 0.0f;
        sync_lds();   // wait for chunk 0

        for (int k = 0; k < NCH; ++k) {
            const float* bufp = &gxs[k & 1][0][0][0];
            // j=0 gx (exposed once per chunk; 6 conflict-free ds_reads)
            float aA[3], aB[3], nA[3], nB[3];
#pragma unroll
            for (int qg = 0; qg < 3; ++qg) {
                aA[qg] = bufp[qg * 128 + tlane];
                aB[qg] = bufp[qg * 128 + 64 + tlane];
            }
#pragma unroll
            for (int j = 0; j < CHUNK; ++j) {
                // prefetch next step's gx (latency hides under this body)
                if (j + 1 < CHUNK) {
#pragma unroll
                    for (int qg = 0; qg < 3; ++qg) {
                        nA[qg] = bufp[((j + 1) * 3 + qg) * 128 + tlane];
                        nB[qg] = bufp[((j + 1) * 3 + qg) * 128 + 64 + tlane];
                    }
                }
                // --- interleaved dual-stream step (independent: B fills A's
                // chain/trans stalls under in-order issue) ---
                float HA[8], HB[8];
                HA[0] = hA;               HB[0] = hB;
                HA[1] = dppf<0xB1>(hA);   HB[1] = dppf<0xB1>(hB);
                HA[2] = dppf<0x4E>(hA);   HB[2] = dppf<0x4E>(hB);
                HA[3] = dppf<0x1B>(hA);   HB[3] = dppf<0x1B>(hB);
                HA[4] = dppf<0x141>(HA[0]); HB[4] = dppf<0x141>(HB[0]);
                HA[5] = dppf<0x141>(HA[1]); HB[5] = dppf<0x141>(HB[1]);
                HA[6] = dppf<0x141>(HA[2]); HB[6] = dppf<0x141>(HB[2]);
                HA[7] = dppf<0x141>(HA[3]); HB[7] = dppf<0x141>(HB[3]);

                float ghA[3], ghB[3];
#pragma unroll
                for (int qg = 0; qg < 3; ++qg) {
                    float a1 = fmaf(whhA[qg][1], HA[1], whhA[qg][0] * HA[0]);
                    float b1 = fmaf(whhB[qg][1], HB[1], whhB[qg][0] * HB[0]);
                    a1 = fmaf(whhA[qg][2], HA[2], a1);
                    b1 = fmaf(whhB[qg][2], HB[2], b1);
                    a1 = fmaf(whhA[qg][3], HA[3], a1);
                    b1 = fmaf(whhB[qg][3], HB[3], b1);
                    float a2 = (qg == 2) ? fmaf(whhA[qg][4], HA[4], bhnA)
                                         : whhA[qg][4] * HA[4];
                    float b2 = (qg == 2) ? fmaf(whhB[qg][4], HB[4], bhnB)
                                         : whhB[qg][4] * HB[4];
                    a2 = fmaf(whhA[qg][5], HA[5], a2);
                    b2 = fmaf(whhB[qg][5], HB[5], b2);
                    a2 = fmaf(whhA[qg][6], HA[6], a2);
                    b2 = fmaf(whhB[qg][6], HB[6], b2);
                    a2 = fmaf(whhA[qg][7], HA[7], a2);
                    b2 = fmaf(whhB[qg][7], HB[7], b2);
                    ghA[qg] = a1 + a2;
                    ghB[qg] = b1 + b2;
                }
                // gates, braided A/B (weights pre-scaled: r,z -log2e; n +2log2e)
                const float eArA = exp2_fast(aA[0] + ghA[0]);
                const float eBrB = exp2_fast(aB[0] + ghB[0]);
                const float eAz  = exp2_fast(aA[1] + ghA[1]);
                const float eBz  = exp2_fast(aB[1] + ghB[1]);
                const float rA = rcp_fast(1.0f + eArA);
                const float rB = rcp_fast(1.0f + eBrB);
                const float zA = rcp_fast(1.0f + eAz);
                const float zB = rcp_fast(1.0f + eBz);
                const float zhA = zA * hA,    zhB = zB * hB;
                const float omA = 1.0f - zA,  omB = 1.0f - zB;
                const float eA = exp2_fast(fmaf(rA, ghA[2], aA[2]));
                const float eB = exp2_fast(fmaf(rB, ghB[2], aB[2]));
                const float nAv = fmaf(-2.0f, rcp_fast(eA + 1.0f), 1.0f);
                const float nBv = fmaf(-2.0f, rcp_fast(eB + 1.0f), 1.0f);
                hA = fmaf(nAv, omA, zhA);
                hB = fmaf(nBv, omB, zhB);
                const size_t trow = (size_t)(k * CHUNK + j) * (Gn * Hn);
                __builtin_nontemporal_store(hA, opA + trow);
                __builtin_nontemporal_store(hB, opB + trow);
                if (j + 1 < CHUNK) {
#pragma unroll
                    for (int qg = 0; qg < 3; ++qg) {
                        aA[qg] = nA[qg];
                        aB[qg] = nB[qg];
                    }
                }
            }
            sync_lds();   // release buffer / wait for next chunk
        }
    }
}

extern "C" void kernel_launch(void* const* d_in, const int* in_sizes, int n_in,
                              void* d_out, int out_size, void* d_ws, size_t ws_size,
                              hipStream_t stream) {
    const float* x    = (const float*)d_in[0];
    const float* W_ih = (const float*)d_in[1];
    const float* W_hh = (const float*)d_in[2];
    const float* b_ih = (const float*)d_in[3];
    const float* b_hh = (const float*)d_in[4];
    float* out = (float*)d_out;

    // 4096 cells / 16 cells-per-block = 256 blocks x 192 threads
    // (1 consumer + 2 producer waves) = 768 waves, <=1 wave/SIMD.
    dim3 grid(256), block(192);
    hipLaunchKernelGGL(mcgru_kernel, grid, block, 0, stream,
                       x, W_ih, W_hh, b_ih, b_hh, out);
}